// Round 3
// baseline (353.461 us; speedup 1.0000x reference)
//
#include <hip/hip_runtime.h>

#define EPS_F 1e-8f

typedef float  f32x4  __attribute__((ext_vector_type(4)));
typedef __bf16 bf16x8 __attribute__((ext_vector_type(8)));
typedef unsigned short u16x4 __attribute__((ext_vector_type(4)));
typedef unsigned short u16x8 __attribute__((ext_vector_type(8)));

// round-to-nearest-even f32 -> bf16 bits (inputs finite; no NaN handling)
__device__ inline unsigned short f2bf(float x) {
  unsigned int u = __float_as_uint(x);
  u += 0x7fffu + ((u >> 16) & 1u);
  return (unsigned short)(u >> 16);
}

// Pre-kernel: normalize each prototype row to unit length, store bf16 bits.
__global__ __launch_bounds__(256) void proto_norm_kernel(
    const float* __restrict__ proto, unsigned short* __restrict__ Bn)
{
  const int tid = threadIdx.x;
  const int g   = tid & 31;
  const int row = blockIdx.x * 8 + (tid >> 5);
  const float4 v = *(const float4*)&proto[row * 128 + g * 4];
  float ss = v.x*v.x + v.y*v.y + v.z*v.z + v.w*v.w;
  #pragma unroll
  for (int m = 16; m >= 1; m >>= 1) ss += __shfl_xor(ss, m);
  const float rn = 1.0f / fmaxf(sqrtf(ss), EPS_F);
  u16x4 b;
  b[0] = f2bf(v.x * rn); b[1] = f2bf(v.y * rn);
  b[2] = f2bf(v.z * rn); b[3] = f2bf(v.w * rn);
  *(u16x4*)&Bn[row * 128 + g * 4] = b;
}

// Main kernel: LDS-free, barrier-free. Wave = 32 rows x 512 cols.
// A in registers (bf16, fused norm); B register-double-buffered from L2.
// MFMA operands swapped so each thread holds 4 consecutive output cols.
__global__ __launch_bounds__(256, 3) void hproto_kernel(
    const float* __restrict__ emb, const unsigned short* __restrict__ Bn,
    float* __restrict__ out)
{
  constexpr int CD = 128;
  constexpr int KP = 512;

  const int tid  = threadIdx.x;
  const int lane = tid & 63;
  const int wave = tid >> 6;
  const int lo   = lane & 15;
  const int hi   = lane >> 4;
  const long rbase = (long)blockIdx.x * 128 + wave * 32;

  bf16x8 bufA[2][4], bufB[2][4];   // [n][kk], 32-col step double buffer
  auto loadB = [&](bf16x8 (&dst)[2][4], int s) {
    const unsigned short* bp = Bn + (s * 32 + lo) * CD + hi * 8;
    #pragma unroll
    for (int n = 0; n < 2; ++n)
      #pragma unroll
      for (int kk = 0; kk < 4; ++kk)
        dst[n][kk] = *(const bf16x8*)(bp + n * 16 * CD + kk * 32);
  };

  loadB(bufA, 0);   // issue first B step before the A-convert VALU burst

  // ---- A: load f32, convert to bf16 in-register, fused row norms ----
  bf16x8 af[2][4];   // [m][kk]; row = rbase + m*16 + lo, k = kk*32 + hi*8
  float  re[2];
  #pragma unroll
  for (int m = 0; m < 2; ++m) {
    const float* rp = emb + (rbase + m * 16 + lo) * CD + hi * 8;
    f32x4 a[4][2];
    #pragma unroll
    for (int kk = 0; kk < 4; ++kk) {
      a[kk][0] = *(const f32x4*)(rp + kk * 32);
      a[kk][1] = *(const f32x4*)(rp + kk * 32 + 4);
    }
    float ss = 0.f;
    #pragma unroll
    for (int kk = 0; kk < 4; ++kk) {
      u16x8 b;
      #pragma unroll
      for (int j = 0; j < 4; ++j) {
        ss += a[kk][0][j] * a[kk][0][j] + a[kk][1][j] * a[kk][1][j];
        b[j]     = f2bf(a[kk][0][j]);
        b[4 + j] = f2bf(a[kk][1][j]);
      }
      af[m][kk] = __builtin_bit_cast(bf16x8, b);
    }
    // 4 lanes (hi=0..3) with same lo jointly hold the full 128-elem row
    ss += __shfl_xor(ss, 16);
    ss += __shfl_xor(ss, 32);
    re[m] = 1.0f / fmaxf(sqrtf(ss), EPS_F);
  }

  float* const ob = out + (rbase + lo) * KP + hi * 4;

  auto compute = [&](bf16x8 (&buf)[2][4], int s) {
    f32x4 acc[2][2];
    #pragma unroll
    for (int m = 0; m < 2; ++m)
      #pragma unroll
      for (int n = 0; n < 2; ++n) acc[m][n] = f32x4{0.f, 0.f, 0.f, 0.f};
    #pragma unroll
    for (int kk = 0; kk < 4; ++kk)
      #pragma unroll
      for (int m = 0; m < 2; ++m)
        #pragma unroll
        for (int n = 0; n < 2; ++n)
          acc[m][n] = __builtin_amdgcn_mfma_f32_16x16x32_bf16(
              buf[n][kk], af[m][kk], acc[m][n], 0, 0, 0);
    // thread holds out[row = rbase+m*16+lo][col = s*32+n*16+hi*4+j], j=0..3
    #pragma unroll
    for (int m = 0; m < 2; ++m)
      #pragma unroll
      for (int n = 0; n < 2; ++n) {
        f32x4 v;
        #pragma unroll
        for (int j = 0; j < 4; ++j) {
          float d = 1.0f - acc[m][n][j] * re[m];
          v[j] = -(d * d);
        }
        __builtin_nontemporal_store(v, (f32x4*)(ob + m * 16 * KP + s * 32 + n * 16));
      }
  };

  // ---- 16 steps of 32 cols, 2-deep register pipeline ----
  #pragma unroll 1
  for (int t = 0; t < 8; ++t) {
    const int s0 = t * 2;
    loadB(bufB, s0 + 1);
    compute(bufA, s0);
    if (t < 7) loadB(bufA, s0 + 2);
    compute(bufB, s0 + 1);
  }
}

extern "C" void kernel_launch(void* const* d_in, const int* in_sizes, int n_in,
                              void* d_out, int out_size, void* d_ws, size_t ws_size,
                              hipStream_t stream) {
  const float* emb   = (const float*)d_in[0];
  const float* proto = (const float*)d_in[1];
  float* out = (float*)d_out;
  unsigned short* Bn = (unsigned short*)d_ws;   // 512*128*2 = 128 KB scratch
  const int C = 128;
  const int N = in_sizes[0] / C;   // 131072
  const int K = in_sizes[1] / C;   // 512
  proto_norm_kernel<<<K / 8, 256, 0, stream>>>(proto, Bn);
  hproto_kernel<<<N / 128, 256, 0, stream>>>(emb, Bn, out);
}